// Round 30
// baseline (349.789 us; speedup 1.0000x reference)
//
#include <hip/hip_runtime.h>
#include <hip/hip_bf16.h>
#include <math.h>

typedef unsigned short u16;
typedef unsigned int u32;
typedef __attribute__((ext_vector_type(8))) short short8;
typedef __attribute__((ext_vector_type(8))) u16 ushort8;
typedef __attribute__((ext_vector_type(4))) float f32x4;
typedef __attribute__((ext_vector_type(16))) float f32x16;
typedef __attribute__((ext_vector_type(4))) u32 u32x4;

#define N_B 4
#define L_S 2048
#define E_D 2048
#define NH 16
#define HD 128
#define WIN 1024
#define QW 3072  // QKV buffer row width: 2048 q | 512 k | 512 v
#define LOG2E 1.4426950408889634f

static __device__ __forceinline__ u16 f32_bf16(float f) {
  u32 u = __builtin_bit_cast(u32, f);
  u = (u + 0x7fffu + ((u >> 16) & 1u)) >> 16;  // RNE
  return (u16)u;
}
static __device__ __forceinline__ float bf16_f32(u16 h) {
  u32 u = ((u32)h) << 16;
  return __builtin_bit_cast(float, u);
}
static __device__ __forceinline__ u32 pack_bf16_pair(float lo, float hi) {
  __hip_bfloat162 h2 = __float22bfloat162_rn(make_float2(lo, hi));  // RNE, .x = low
  u32 r;
  __builtin_memcpy(&r, &h2, 4);
  return r;
}
static __device__ __forceinline__ void gload_lds16(const void* g, void* l) {
  __builtin_amdgcn_global_load_lds((__attribute__((address_space(1))) void*)g,
                                   (__attribute__((address_space(3))) void*)l, 16, 0, 0);
}

// ---------------- fp32 -> bf16 cast (n multiple of 8) ----------------
__global__ void k_cast(const float* __restrict__ src, u16* __restrict__ dst, int n8) {
  int i = blockIdx.x * blockDim.x + threadIdx.x;
  if (i >= n8) return;
  const float4* s = (const float4*)src + (size_t)i * 2;
  float4 a = s[0], b = s[1];
  ushort8 v;
  v[0] = f32_bf16(a.x); v[1] = f32_bf16(a.y); v[2] = f32_bf16(a.z); v[3] = f32_bf16(a.w);
  v[4] = f32_bf16(b.x); v[5] = f32_bf16(b.y); v[6] = f32_bf16(b.z); v[7] = f32_bf16(b.w);
  *((ushort8*)dst + i) = v;
}

// ------- all 4 weight casts + RoPE table in one launch (block-range switch) -------
__global__ void k_cast_w(const float* __restrict__ Wq, const float* __restrict__ Wk,
                         const float* __restrict__ Wv, const float* __restrict__ Wo,
                         u16* __restrict__ Wqkv, u16* __restrict__ Wob,
                         float* __restrict__ cs, float* __restrict__ sn) {
  int bb = blockIdx.x;
  if (bb >= 5120) {  // RoPE table: [L][64]
    int idx = (bb - 5120) * 256 + threadIdx.x;  // 2048*64
    int l = idx >> 6, f = idx & 63;
    float freq = exp2f(-(float)f * (13.287712379549449f / 64.0f));  // 10000^(-2f/128)
    float ang = (float)l * freq;
    cs[idx] = cosf(ang);
    sn[idx] = sinf(ang);
    return;
  }
  const float* src;
  u16* dst;
  int base;
  if (bb < 2048)      { src = Wq; dst = Wqkv;                 base = bb; }
  else if (bb < 2560) { src = Wk; dst = Wqkv + 2048 * 2048;   base = bb - 2048; }
  else if (bb < 3072) { src = Wv; dst = Wqkv + 2560 * 2048;   base = bb - 2560; }
  else                { src = Wo; dst = Wob;                  base = bb - 3072; }
  int i = base * 256 + threadIdx.x;
  const float4* s = (const float4*)src + (size_t)i * 2;
  float4 a = s[0], b = s[1];
  ushort8 v;
  v[0] = f32_bf16(a.x); v[1] = f32_bf16(a.y); v[2] = f32_bf16(a.z); v[3] = f32_bf16(a.w);
  v[4] = f32_bf16(b.x); v[5] = f32_bf16(b.y); v[6] = f32_bf16(b.z); v[7] = f32_bf16(b.w);
  *((ushort8*)dst + i) = v;
}

// ---------------- interleaved RoPE applied in place to K region of QKV --------------
__global__ void k_rope_k(u16* __restrict__ QKV, const float* __restrict__ cs,
                         const float* __restrict__ sn) {
  int idx = blockIdx.x * blockDim.x + threadIdx.x;  // 8192*4*64 exactly
  int f = idx & 63;
  int rest = idx >> 6;
  int hh = rest & 3;           // kv head 0..3
  int row = rest >> 2;         // 0..8191 (= n*L + l)
  int l = row & (L_S - 1);
  int col = E_D + hh * HD + 2 * f;
  u32* p = (u32*)(QKV + (size_t)row * QW + col);
  u32 v = *p;
  float xr = bf16_f32((u16)(v & 0xffffu));
  float xi = bf16_f32((u16)(v >> 16));
  float c = cs[l * 64 + f], s = sn[l * 64 + f];
  float orr = xr * c - xi * s;
  float oii = xr * s + xi * c;
  *p = (u32)f32_bf16(orr) | ((u32)f32_bf16(oii) << 16);
}

// ---------------- C = A @ B^T, 256xBN tile, BK=32, 8-phase counted-vmcnt ----
// (measured best GEMM configuration)
template <int OUT_F32, int BN>
__global__ __launch_bounds__(512, 1) void k_gemm8(
    const u16* __restrict__ A, int lda,
    const u16* __restrict__ B, int ldb,
    void* __restrict__ Cp, int ldc, int K) {
  constexpr int NF = BN / 64;        // B-frags per wave (4 or 2)
  constexpr int PB = BN / 128;       // gloads per B stage (2 or 1)
  constexpr int BBY = BN * 64;       // bytes per B buffer
  constexpr int LVM = 2 + PB;        // per-tile load count -> vmcnt(LVM)
  __shared__ __align__(16) u16 Ab[3 * 8192];      // 3 x [256][32]
  __shared__ __align__(16) u16 Bb[3 * (BN * 32)]; // 3 x [BN][32]
  const int tid = threadIdx.x;
  const int lane = tid & 63, w = tid >> 6;
  const int lr = lane & 15, lg = lane >> 4;
  const int wm = w >> 2, wn = w & 3;
  const int fid = blockIdx.x;
  const int cc = fid & 7, l = fid >> 3;
  const int m0 = (cc * 4 + (l & 3)) * 256;
  const int n0 = (l >> 2) * BN;
  const int rswz = (lr & 6) << 3;  // read-side XOR (row bits 1-2)

  const int r2 = tid >> 2;                                   // 0..127
  const int ce = (((tid & 3) * 16) ^ ((r2 & 6) << 3)) >> 1;  // pre-swizzled src col
  auto STAGE_A = [&](int kt, int bb) {
#pragma unroll
    for (int rr = 0; rr < 2; ++rr)
      gload_lds16(A + (size_t)(m0 + rr * 128 + r2) * lda + kt * 32 + ce,
                  (char*)Ab + bb * 16384 + rr * 8192 + (w << 10));
  };
  auto STAGE_B = [&](int kt, int bb) {
#pragma unroll
    for (int rr = 0; rr < PB; ++rr)
      gload_lds16(B + (size_t)(n0 + rr * 128 + r2) * ldb + kt * 32 + ce,
                  (char*)Bb + bb * BBY + rr * 8192 + (w << 10));
  };

  f32x4 acc[8][NF];
  const f32x4 z4 = {0.f, 0.f, 0.f, 0.f};
#pragma unroll
  for (int mf = 0; mf < 8; ++mf)
#pragma unroll
    for (int nf = 0; nf < NF; ++nf) acc[mf][nf] = z4;

  const int nt = K >> 5;  // K-tiles of 32 (K=2048 -> 64)
  STAGE_A(0, 0); STAGE_B(0, 0);
  STAGE_A(1, 1); STAGE_B(1, 1);
  asm volatile("s_waitcnt vmcnt(%0)" :: "i"(LVM) : "memory");  // tile0 published
  __builtin_amdgcn_sched_barrier(0);
  __builtin_amdgcn_s_barrier();
  __builtin_amdgcn_sched_barrier(0);

  int c3 = 0;
  for (int t = 0; t < nt; ++t) {
    int ib = c3 + 2; if (ib >= 3) ib -= 3;
    const char* Abt = (const char*)Ab + c3 * 16384;
    const char* Bbt = (const char*)Bb + c3 * BBY;
    short8 af[4], bf[NF];
    // ---- phase 0: quadrant qm=0 ----
#pragma unroll
    for (int nf = 0; nf < NF; ++nf) {
      int row = wn * (BN / 4) + nf * 16 + lr;
      bf[nf] = *(const short8*)(Bbt + row * 64 + ((lg * 16) ^ rswz));
    }
#pragma unroll
    for (int mf = 0; mf < 4; ++mf) {
      int row = wm * 128 + mf * 16 + lr;
      af[mf] = *(const short8*)(Abt + row * 64 + ((lg * 16) ^ rswz));
    }
    if (t + 2 < nt) STAGE_A(t + 2, ib);
    __builtin_amdgcn_sched_barrier(0);
    __builtin_amdgcn_s_barrier();
    asm volatile("s_waitcnt lgkmcnt(0)" ::: "memory");
    __builtin_amdgcn_sched_barrier(0);
    __builtin_amdgcn_s_setprio(1);
#pragma unroll
    for (int mf = 0; mf < 4; ++mf)
#pragma unroll
      for (int nf = 0; nf < NF; ++nf)
        acc[mf][nf] =
            __builtin_amdgcn_mfma_f32_16x16x32_bf16(af[mf], bf[nf], acc[mf][nf], 0, 0, 0);
    __builtin_amdgcn_s_setprio(0);
    __builtin_amdgcn_sched_barrier(0);
    __builtin_amdgcn_s_barrier();
    __builtin_amdgcn_sched_barrier(0);
    // ---- phase 1: quadrant qm=1 (bf carried in registers) ----
#pragma unroll
    for (int mf = 0; mf < 4; ++mf) {
      int row = wm * 128 + 64 + mf * 16 + lr;
      af[mf] = *(const short8*)(Abt + row * 64 + ((lg * 16) ^ rswz));
    }
    if (t + 2 < nt) STAGE_B(t + 2, ib);
    if (t + 2 < nt)
      asm volatile("s_waitcnt vmcnt(%0)" :: "i"(LVM) : "memory");
    else
      asm volatile("s_waitcnt vmcnt(0)" ::: "memory");
    __builtin_amdgcn_sched_barrier(0);
    __builtin_amdgcn_s_barrier();
    asm volatile("s_waitcnt lgkmcnt(0)" ::: "memory");
    __builtin_amdgcn_sched_barrier(0);
    __builtin_amdgcn_s_setprio(1);
#pragma unroll
    for (int mf = 0; mf < 4; ++mf)
#pragma unroll
      for (int nf = 0; nf < NF; ++nf)
        acc[4 + mf][nf] =
            __builtin_amdgcn_mfma_f32_16x16x32_bf16(af[mf], bf[nf], acc[4 + mf][nf], 0, 0, 0);
    __builtin_amdgcn_s_setprio(0);
    __builtin_amdgcn_sched_barrier(0);
    __builtin_amdgcn_s_barrier();
    __builtin_amdgcn_sched_barrier(0);
    c3 = (c3 == 2) ? 0 : c3 + 1;
  }

#pragma unroll
  for (int mf = 0; mf < 8; ++mf)
#pragma unroll
    for (int nf = 0; nf < NF; ++nf)
#pragma unroll
      for (int j = 0; j < 4; ++j) {
        size_t r = (size_t)(m0 + wm * 128 + mf * 16 + lg * 4 + j);
        int c = n0 + wn * (BN / 4) + nf * 16 + lr;
        if (OUT_F32)
          ((float*)Cp)[r * ldc + c] = acc[mf][nf][j];
        else
          ((u16*)Cp)[r * ldc + c] = f32_bf16(acc[mf][nf][j]);
      }
}

// ---------------- sliding-window flash attention (8 waves, counted-vmcnt pipeline) --
// K prefetch 2-deep into 3 LDS buffers; V single-buffered; raw barriers with
// counted vmcnt (never 0 mid-loop); fused Q-rope; in-register P via partner-lane
// shfl_xor(32); defer-max; interior-tile fast path. Best-measured variant.
__global__ __launch_bounds__(512, 2) void k_attn(u16* __restrict__ QKV,
                                                 const float* __restrict__ cs,
                                                 const float* __restrict__ sn) {
  const int bx = blockIdx.x, h = blockIdx.y, b = blockIdx.z;
  const int qb = (b >= 2) ? 7 - bx : bx;        // cost-balanced remap
  const int tid = threadIdx.x;
  const int lane = tid & 63, w = tid >> 6;      // 8 waves
  const int l31 = lane & 31, hi = lane >> 5;
  const int kh = h >> 2;
  const int qs = qb * 256 + w * 32;
  __shared__ __align__(16) u16 Klds[3][64 * 128];  // [kv][d], swizzled, 3 buffers
  __shared__ __align__(16) u16 Vt[128 * 64];       // [d][kv], swizzled, 1 buffer
  char* Vb = (char*)Vt;
  const float SCL2 = 0.08838834764831845f * 1.4426950408889634f;  // scale*log2(e)
  const size_t bL = (size_t)b * L_S;
  const int q = qs + l31;
  const size_t rowQ = (bL + q) * QW + h * HD;
  // Q load + fused interleaved RoPE (d = ds*16+hi*8+j; pair f = d>>1)
  short8 qf[8];
#pragma unroll
  for (int ds = 0; ds < 8; ++ds) {
    short8 qr = *(const short8*)(QKV + rowQ + ds * 16 + hi * 8);
    const int f0 = ds * 8 + hi * 4;                   // first pair index (mult of 4)
    float4 c4 = *(const float4*)(cs + (size_t)q * 64 + f0);
    float4 s4 = *(const float4*)(sn + (size_t)q * 64 + f0);
    ushort8 qo;
#pragma unroll
    for (int e = 0; e < 4; ++e) {
      float xr = bf16_f32((u16)qr[2 * e]);
      float xi = bf16_f32((u16)qr[2 * e + 1]);
      float co = (e == 0) ? c4.x : (e == 1) ? c4.y : (e == 2) ? c4.z : c4.w;
      float si = (e == 0) ? s4.x : (e == 1) ? s4.y : (e == 2) ? s4.z : s4.w;
      qo[2 * e]     = f32_bf16(xr * co - xi * si);
      qo[2 * e + 1] = f32_bf16(xr * si + xi * co);
    }
    qf[ds] = __builtin_bit_cast(short8, qo);
  }
  f32x16 o[4];
#pragma unroll
  for (int dt = 0; dt < 4; ++dt)
#pragma unroll
    for (int r = 0; r < 16; ++r) o[dt][r] = 0.f;
  float m2 = -3e38f, lsum = 0.f;  // per-lane stats for this lane's q (log2 domain)
  int t0 = qb * 256 - (WIN - 1);
  if (t0 < 0) t0 = 0;
  t0 >>= 6;
  const int t1 = 4 * qb + 3;  // == (qb*256+255)>>6 (always >= t0+3)
  short8 vreg[2];

  auto ISSUE_K = [&](int t, int buf) {
    char* Kb = (char*)Klds + buf * 16384;
#pragma unroll
    for (int rr = 0; rr < 2; ++rr) {
      int row = rr * 32 + (tid >> 4);              // 0..63
      int colb = ((tid & 15) * 16) ^ ((row & 7) << 4);  // inverse-swizzled source
      gload_lds16(QKV + (bL + t * 64 + row) * QW + E_D + kh * HD + (colb >> 1),
                  Kb + rr * 8192 + w * 1024 + (lane << 4));
    }
  };
  auto LOAD_V = [&](int t) {
#pragma unroll
    for (int rr = 0; rr < 2; ++rr)
      vreg[rr] = *(const short8*)(QKV + (bL + t * 64 + lane) * QW + E_D + 512 + kh * HD +
                                  ((w * 2 + rr) * 8));
  };
  auto WRITE_V = [&]() {
#pragma unroll
    for (int rr = 0; rr < 2; ++rr) {
      int db = (w * 2 + rr) * 8;                   // multiple of 8 -> row&7 == e
#pragma unroll
      for (int e = 0; e < 8; ++e)
        *(u16*)(Vb + ((((db + e) * 128) + lane * 2) ^ (e << 4))) = (u16)vreg[rr][e];
    }
  };

  // --- prologue ---
  LOAD_V(t0);
  ISSUE_K(t0, t0 % 3);
  ISSUE_K(t0 + 1, (t0 + 1) % 3);
  __syncthreads();          // full drain (prologue only); Vt write next
  WRITE_V();                // Vt = V(t0); published by barrier1 of iter t0

  for (int t = t0; t <= t1; ++t) {
    const int kv0 = t * 64;
    const bool haveV = (t + 1 <= t1);
    const bool haveK = (t + 2 <= t1);
    if (haveV) LOAD_V(t + 1);                 // issue V FIRST
    if (haveK) ISSUE_K(t + 2, (t + 2) % 3);   // then K (stays in flight longer)
    const bool act = (kv0 <= qs + 31) && (kv0 + 63 > qs - WIN);
    const bool full = (kv0 + 63 <= qs) && (kv0 > qs + 31 - WIN);  // no masking needed
    u32x4 pa[4];  // assembled PV A-frags (bf16 x8 each)
    if (act) {
      const char* Kb = (const char*)Klds + (t % 3) * 16384;
      f32x16 s[2];
#pragma unroll
      for (int g = 0; g < 2; ++g)
#pragma unroll
        for (int r = 0; r < 16; ++r) s[g][r] = 0.f;
#pragma unroll
      for (int g = 0; g < 2; ++g) {
        const int r = g * 32 + l31;                  // K row this lane reads
        const int rsw = (r & 7) << 4;
#pragma unroll
        for (int ds = 0; ds < 8; ++ds) {
          short8 kf = *(const short8*)(Kb + (r * 256 + ((ds * 32 + hi * 16) ^ rsw)));
          s[g] = __builtin_amdgcn_mfma_f32_32x32x16_bf16(kf, qf[ds], s[g], 0, 0, 0);
        }
      }
      float v[2][16];
      float mx = -3e38f;
      if (full) {
#pragma unroll
        for (int g = 0; g < 2; ++g)
#pragma unroll
          for (int r = 0; r < 16; ++r) {
            float vv = s[g][r] * SCL2;
            v[g][r] = vv;
            mx = fmaxf(mx, vv);
          }
      } else {
#pragma unroll
        for (int g = 0; g < 2; ++g)
#pragma unroll
          for (int r = 0; r < 16; ++r) {
            int kg = kv0 + g * 32 + (r & 3) + 8 * (r >> 2) + 4 * hi;
            bool a = (kg <= q) && (kg > q - WIN);
            float vv = a ? s[g][r] * SCL2 : -3e38f;
            v[g][r] = vv;
            mx = fmaxf(mx, vv);
          }
      }
      mx = fmaxf(mx, __shfl_xor(mx, 32));            // partner has other kv half
      if (__ballot(mx > m2 + 11.5415603f)) {
        float mn = fmaxf(m2, mx);
        float alpha = exp2f(m2 - mn);
        m2 = mn;
        lsum *= alpha;
#pragma unroll
        for (int r = 0; r < 16; ++r) {
          float alr = __shfl(alpha, (r & 3) + 8 * (r >> 2) + 4 * hi);
#pragma unroll
          for (int dt = 0; dt < 4; ++dt) o[dt][r] *= alr;
        }
      }
      float rs = 0.f;
      if (full) {
#pragma unroll
        for (int g = 0; g < 2; ++g)
#pragma unroll
          for (int r = 0; r < 16; ++r) {
            float pe = exp2f(v[g][r] - m2);
            v[g][r] = pe;
            rs += pe;
          }
      } else {
#pragma unroll
        for (int g = 0; g < 2; ++g)
#pragma unroll
          for (int r = 0; r < 16; ++r) {
            float pe = (v[g][r] > -1e37f) ? exp2f(v[g][r] - m2) : 0.f;
            v[g][r] = pe;
            rs += pe;
          }
      }
      rs += __shfl_xor(rs, 32);
      lsum += rs;
#pragma unroll
      for (int g = 0; g < 2; ++g) {
        u32 W[8];
#pragma unroll
        for (int qi = 0; qi < 4; ++qi) {
          W[2 * qi]     = pack_bf16_pair(v[g][4 * qi + 0], v[g][4 * qi + 1]);
          W[2 * qi + 1] = pack_bf16_pair(v[g][4 * qi + 2], v[g][4 * qi + 3]);
        }
        u32 R[4];
        R[0] = __shfl_xor(hi ? W[0] : W[2], 32);
        R[1] = __shfl_xor(hi ? W[1] : W[3], 32);
        R[2] = __shfl_xor(hi ? W[4] : W[6], 32);
        R[3] = __shfl_xor(hi ? W[5] : W[7], 32);
#pragma unroll
        for (int ksl = 0; ksl < 2; ++ksl) {
          u32x4 fr;
          if (hi == 0) {
            fr[0] = W[4 * ksl]; fr[1] = W[4 * ksl + 1];
            fr[2] = R[2 * ksl]; fr[3] = R[2 * ksl + 1];
          } else {
            fr[0] = R[2 * ksl]; fr[1] = R[2 * ksl + 1];
            fr[2] = W[4 * ksl + 2]; fr[3] = W[4 * ksl + 3];
          }
          pa[g * 2 + ksl] = fr;
        }
      }
    }
    // barrier1: publishes Vt (writer's ds_writes drained) + orders LDS reuse
    asm volatile("s_waitcnt lgkmcnt(0)" ::: "memory");
    __builtin_amdgcn_sched_barrier(0);
    __builtin_amdgcn_s_barrier();
    __builtin_amdgcn_sched_barrier(0);
    if (act) {
      // --- O += P V from Vt ---
      __builtin_amdgcn_s_setprio(1);
#pragma unroll
      for (int dt = 0; dt < 4; ++dt) {
        const int d = dt * 32 + l31;
        const int dsw = (d & 7) << 4;
#pragma unroll
        for (int ks = 0; ks < 4; ++ks) {
          short8 vf = *(const short8*)(Vb + (d * 128 + ((ks * 32 + hi * 16) ^ dsw)));
          o[dt] = __builtin_amdgcn_mfma_f32_32x32x16_bf16(
              __builtin_bit_cast(short8, pa[ks]), vf, o[dt], 0, 0, 0);
        }
      }
      __builtin_amdgcn_s_setprio(0);
    }
    // barrier2: counted vmcnt — drain K(t+1) (next QK input), keep newest in flight
    if (haveK)
      asm volatile("s_waitcnt vmcnt(4)" ::: "memory");
    else if (haveV)
      asm volatile("s_waitcnt vmcnt(2)" ::: "memory");
    else
      asm volatile("s_waitcnt vmcnt(0)" ::: "memory");
    __builtin_amdgcn_sched_barrier(0);
    __builtin_amdgcn_s_barrier();
    __builtin_amdgcn_sched_barrier(0);
    if (haveV) WRITE_V();   // Vt = V(t+1); readers gated by barrier1(t+1)
  }
  float inv = 1.0f / lsum;
#pragma unroll
  for (int r = 0; r < 16; ++r) {
    int ridx = (r & 3) + 8 * (r >> 2) + 4 * hi;
    float invr = __shfl(inv, ridx);
    size_t rowO = (bL + qs + ridx) * QW + h * HD + l31;
#pragma unroll
    for (int dt = 0; dt < 4; ++dt)
      QKV[rowO + dt * 32] = f32_bf16(o[dt][r] * invr);
  }
}

extern "C" void kernel_launch(void* const* d_in, const int* in_sizes, int n_in,
                              void* d_out, int out_size, void* d_ws, size_t ws_size,
                              hipStream_t stream) {
  const float* x  = (const float*)d_in[0];
  const float* Wq = (const float*)d_in[1];
  const float* Wk = (const float*)d_in[2];
  const float* Wv = (const float*)d_in[3];
  const float* Wo = (const float*)d_in[4];
  char* ws = (char*)d_ws;
  // Workspace layout (total 105,906,176 B). If the harness workspace is too
  // small, bail out cleanly (validation fails loudly instead of GPU faulting).
  if (ws_size < 105906176u) return;
  u16* xb    = (u16*)(ws);                    // 8192*2048*2 = 33554432
  u16* Wqkv  = (u16*)(ws + 33554432);         // 3072*2048*2 = 12582912
  u16* Wob   = (u16*)(ws + 46137344);         // 2048*2048*2 =  8388608
  u16* QKV   = (u16*)(ws + 54525952);         // 8192*3072*2 = 50331648
  float* cs  = (float*)(ws + 104857600);      // 131072*4    =   524288
  float* sn  = (float*)(ws + 105381888);      // total end 105906176 B

  // bf16 casts + RoPE table (weights packed: Wq 0..2047 | Wk 2048..2559 | Wv 2560..3071)
  k_cast<<<8192, 256, 0, stream>>>(x, xb, 16777216 / 8);
  k_cast_w<<<5632, 256, 0, stream>>>(Wq, Wk, Wv, Wo, Wqkv, Wob, cs, sn);
  // fused QKV projection: [Q|K|V] = xb @ Wqkv^T (256x128 tiles: 32 m x 24 n = 768 wg)
  k_gemm8<0, 128><<<768, 512, 0, stream>>>(xb, 2048, Wqkv, 2048, QKV, QW, 2048);
  // RoPE in place on K region only (Q rope fused into k_attn)
  k_rope_k<<<8192, 256, 0, stream>>>(QKV, cs, sn);
  // flash attention (Q-rope fused, counted-vmcnt pipeline); Z overwrites Q region
  k_attn<<<dim3(8, 16, 4), 512, 0, stream>>>(QKV, cs, sn);
  // out = Z @ Wo^T (fp32 out; 256x256 tiles: 32 m x 8 n = 256 wg, exact fit)
  k_gemm8<1, 256><<<256, 512, 0, stream>>>(QKV, QW, Wob, 2048, d_out, 2048, 2048);
}

// Round 31
// 348.832 us; speedup vs baseline: 1.0027x; 1.0027x over previous
//
#include <hip/hip_runtime.h>
#include <hip/hip_bf16.h>
#include <math.h>

typedef unsigned short u16;
typedef unsigned int u32;
typedef __attribute__((ext_vector_type(8))) short short8;
typedef __attribute__((ext_vector_type(8))) u16 ushort8;
typedef __attribute__((ext_vector_type(4))) float f32x4;
typedef __attribute__((ext_vector_type(16))) float f32x16;
typedef __attribute__((ext_vector_type(4))) u32 u32x4;

#define N_B 4
#define L_S 2048
#define E_D 2048
#define NH 16
#define HD 128
#define WIN 1024
#define QW 3072  // QKV buffer row width: 2048 q | 512 k | 512 v
#define LOG2E 1.4426950408889634f

static __device__ __forceinline__ u16 f32_bf16(float f) {
  u32 u = __builtin_bit_cast(u32, f);
  u = (u + 0x7fffu + ((u >> 16) & 1u)) >> 16;  // RNE
  return (u16)u;
}
static __device__ __forceinline__ float bf16_f32(u16 h) {
  u32 u = ((u32)h) << 16;
  return __builtin_bit_cast(float, u);
}
static __device__ __forceinline__ u32 pack_bf16_pair(float lo, float hi) {
  __hip_bfloat162 h2 = __float22bfloat162_rn(make_float2(lo, hi));  // RNE, .x = low
  u32 r;
  __builtin_memcpy(&r, &h2, 4);
  return r;
}
static __device__ __forceinline__ void gload_lds16(const void* g, void* l) {
  __builtin_amdgcn_global_load_lds((__attribute__((address_space(1))) void*)g,
                                   (__attribute__((address_space(3))) void*)l, 16, 0, 0);
}

// ---------------- fp32 -> bf16 cast (n multiple of 8) ----------------
__global__ void k_cast(const float* __restrict__ src, u16* __restrict__ dst, int n8) {
  int i = blockIdx.x * blockDim.x + threadIdx.x;
  if (i >= n8) return;
  const float4* s = (const float4*)src + (size_t)i * 2;
  float4 a = s[0], b = s[1];
  ushort8 v;
  v[0] = f32_bf16(a.x); v[1] = f32_bf16(a.y); v[2] = f32_bf16(a.z); v[3] = f32_bf16(a.w);
  v[4] = f32_bf16(b.x); v[5] = f32_bf16(b.y); v[6] = f32_bf16(b.z); v[7] = f32_bf16(b.w);
  *((ushort8*)dst + i) = v;
}

// ------- all 4 weight casts + RoPE table in one launch (block-range switch) -------
__global__ void k_cast_w(const float* __restrict__ Wq, const float* __restrict__ Wk,
                         const float* __restrict__ Wv, const float* __restrict__ Wo,
                         u16* __restrict__ Wqkv, u16* __restrict__ Wob,
                         float* __restrict__ cs, float* __restrict__ sn) {
  int bb = blockIdx.x;
  if (bb >= 5120) {  // RoPE table: [L][64]
    int idx = (bb - 5120) * 256 + threadIdx.x;  // 2048*64
    int l = idx >> 6, f = idx & 63;
    float freq = exp2f(-(float)f * (13.287712379549449f / 64.0f));  // 10000^(-2f/128)
    float ang = (float)l * freq;
    cs[idx] = cosf(ang);
    sn[idx] = sinf(ang);
    return;
  }
  const float* src;
  u16* dst;
  int base;
  if (bb < 2048)      { src = Wq; dst = Wqkv;                 base = bb; }
  else if (bb < 2560) { src = Wk; dst = Wqkv + 2048 * 2048;   base = bb - 2048; }
  else if (bb < 3072) { src = Wv; dst = Wqkv + 2560 * 2048;   base = bb - 2560; }
  else                { src = Wo; dst = Wob;                  base = bb - 3072; }
  int i = base * 256 + threadIdx.x;
  const float4* s = (const float4*)src + (size_t)i * 2;
  float4 a = s[0], b = s[1];
  ushort8 v;
  v[0] = f32_bf16(a.x); v[1] = f32_bf16(a.y); v[2] = f32_bf16(a.z); v[3] = f32_bf16(a.w);
  v[4] = f32_bf16(b.x); v[5] = f32_bf16(b.y); v[6] = f32_bf16(b.z); v[7] = f32_bf16(b.w);
  *((ushort8*)dst + i) = v;
}

// ---------------- interleaved RoPE applied in place to K region of QKV --------------
__global__ void k_rope_k(u16* __restrict__ QKV, const float* __restrict__ cs,
                         const float* __restrict__ sn) {
  int idx = blockIdx.x * blockDim.x + threadIdx.x;  // 8192*4*64 exactly
  int f = idx & 63;
  int rest = idx >> 6;
  int hh = rest & 3;           // kv head 0..3
  int row = rest >> 2;         // 0..8191 (= n*L + l)
  int l = row & (L_S - 1);
  int col = E_D + hh * HD + 2 * f;
  u32* p = (u32*)(QKV + (size_t)row * QW + col);
  u32 v = *p;
  float xr = bf16_f32((u16)(v & 0xffffu));
  float xi = bf16_f32((u16)(v >> 16));
  float c = cs[l * 64 + f], s = sn[l * 64 + f];
  float orr = xr * c - xi * s;
  float oii = xr * s + xi * c;
  *p = (u32)f32_bf16(orr) | ((u32)f32_bf16(oii) << 16);
}

// ---------------- C = A @ B^T, 256xBN tile, BK=32, 8-phase counted-vmcnt ----
// (measured best GEMM configuration)
template <int OUT_F32, int BN>
__global__ __launch_bounds__(512, 1) void k_gemm8(
    const u16* __restrict__ A, int lda,
    const u16* __restrict__ B, int ldb,
    void* __restrict__ Cp, int ldc, int K) {
  constexpr int NF = BN / 64;        // B-frags per wave (4 or 2)
  constexpr int PB = BN / 128;       // gloads per B stage (2 or 1)
  constexpr int BBY = BN * 64;       // bytes per B buffer
  constexpr int LVM = 2 + PB;        // per-tile load count -> vmcnt(LVM)
  __shared__ __align__(16) u16 Ab[3 * 8192];      // 3 x [256][32]
  __shared__ __align__(16) u16 Bb[3 * (BN * 32)]; // 3 x [BN][32]
  const int tid = threadIdx.x;
  const int lane = tid & 63, w = tid >> 6;
  const int lr = lane & 15, lg = lane >> 4;
  const int wm = w >> 2, wn = w & 3;
  const int fid = blockIdx.x;
  const int cc = fid & 7, l = fid >> 3;
  const int m0 = (cc * 4 + (l & 3)) * 256;
  const int n0 = (l >> 2) * BN;
  const int rswz = (lr & 6) << 3;  // read-side XOR (row bits 1-2)

  const int r2 = tid >> 2;                                   // 0..127
  const int ce = (((tid & 3) * 16) ^ ((r2 & 6) << 3)) >> 1;  // pre-swizzled src col
  auto STAGE_A = [&](int kt, int bb) {
#pragma unroll
    for (int rr = 0; rr < 2; ++rr)
      gload_lds16(A + (size_t)(m0 + rr * 128 + r2) * lda + kt * 32 + ce,
                  (char*)Ab + bb * 16384 + rr * 8192 + (w << 10));
  };
  auto STAGE_B = [&](int kt, int bb) {
#pragma unroll
    for (int rr = 0; rr < PB; ++rr)
      gload_lds16(B + (size_t)(n0 + rr * 128 + r2) * ldb + kt * 32 + ce,
                  (char*)Bb + bb * BBY + rr * 8192 + (w << 10));
  };

  f32x4 acc[8][NF];
  const f32x4 z4 = {0.f, 0.f, 0.f, 0.f};
#pragma unroll
  for (int mf = 0; mf < 8; ++mf)
#pragma unroll
    for (int nf = 0; nf < NF; ++nf) acc[mf][nf] = z4;

  const int nt = K >> 5;  // K-tiles of 32 (K=2048 -> 64)
  STAGE_A(0, 0); STAGE_B(0, 0);
  STAGE_A(1, 1); STAGE_B(1, 1);
  asm volatile("s_waitcnt vmcnt(%0)" :: "i"(LVM) : "memory");  // tile0 published
  __builtin_amdgcn_sched_barrier(0);
  __builtin_amdgcn_s_barrier();
  __builtin_amdgcn_sched_barrier(0);

  int c3 = 0;
  for (int t = 0; t < nt; ++t) {
    int ib = c3 + 2; if (ib >= 3) ib -= 3;
    const char* Abt = (const char*)Ab + c3 * 16384;
    const char* Bbt = (const char*)Bb + c3 * BBY;
    short8 af[4], bf[NF];
    // ---- phase 0: quadrant qm=0 ----
#pragma unroll
    for (int nf = 0; nf < NF; ++nf) {
      int row = wn * (BN / 4) + nf * 16 + lr;
      bf[nf] = *(const short8*)(Bbt + row * 64 + ((lg * 16) ^ rswz));
    }
#pragma unroll
    for (int mf = 0; mf < 4; ++mf) {
      int row = wm * 128 + mf * 16 + lr;
      af[mf] = *(const short8*)(Abt + row * 64 + ((lg * 16) ^ rswz));
    }
    if (t + 2 < nt) STAGE_A(t + 2, ib);
    __builtin_amdgcn_sched_barrier(0);
    __builtin_amdgcn_s_barrier();
    asm volatile("s_waitcnt lgkmcnt(0)" ::: "memory");
    __builtin_amdgcn_sched_barrier(0);
    __builtin_amdgcn_s_setprio(1);
#pragma unroll
    for (int mf = 0; mf < 4; ++mf)
#pragma unroll
      for (int nf = 0; nf < NF; ++nf)
        acc[mf][nf] =
            __builtin_amdgcn_mfma_f32_16x16x32_bf16(af[mf], bf[nf], acc[mf][nf], 0, 0, 0);
    __builtin_amdgcn_s_setprio(0);
    __builtin_amdgcn_sched_barrier(0);
    __builtin_amdgcn_s_barrier();
    __builtin_amdgcn_sched_barrier(0);
    // ---- phase 1: quadrant qm=1 (bf carried in registers) ----
#pragma unroll
    for (int mf = 0; mf < 4; ++mf) {
      int row = wm * 128 + 64 + mf * 16 + lr;
      af[mf] = *(const short8*)(Abt + row * 64 + ((lg * 16) ^ rswz));
    }
    if (t + 2 < nt) STAGE_B(t + 2, ib);
    if (t + 2 < nt)
      asm volatile("s_waitcnt vmcnt(%0)" :: "i"(LVM) : "memory");
    else
      asm volatile("s_waitcnt vmcnt(0)" ::: "memory");
    __builtin_amdgcn_sched_barrier(0);
    __builtin_amdgcn_s_barrier();
    asm volatile("s_waitcnt lgkmcnt(0)" ::: "memory");
    __builtin_amdgcn_sched_barrier(0);
    __builtin_amdgcn_s_setprio(1);
#pragma unroll
    for (int mf = 0; mf < 4; ++mf)
#pragma unroll
      for (int nf = 0; nf < NF; ++nf)
        acc[4 + mf][nf] =
            __builtin_amdgcn_mfma_f32_16x16x32_bf16(af[mf], bf[nf], acc[4 + mf][nf], 0, 0, 0);
    __builtin_amdgcn_s_setprio(0);
    __builtin_amdgcn_sched_barrier(0);
    __builtin_amdgcn_s_barrier();
    __builtin_amdgcn_sched_barrier(0);
    c3 = (c3 == 2) ? 0 : c3 + 1;
  }

#pragma unroll
  for (int mf = 0; mf < 8; ++mf)
#pragma unroll
    for (int nf = 0; nf < NF; ++nf)
#pragma unroll
      for (int j = 0; j < 4; ++j) {
        size_t r = (size_t)(m0 + wm * 128 + mf * 16 + lg * 4 + j);
        int c = n0 + wn * (BN / 4) + nf * 16 + lr;
        if (OUT_F32)
          ((float*)Cp)[r * ldc + c] = acc[mf][nf][j];
        else
          ((u16*)Cp)[r * ldc + c] = f32_bf16(acc[mf][nf][j]);
      }
}

// ---------------- sliding-window flash attention (8 waves, counted-vmcnt pipeline) --
// K prefetch 2-deep into 3 LDS buffers; V single-buffered; raw barriers with
// counted vmcnt (never 0 mid-loop); fused Q-rope; in-register P via partner-lane
// shfl_xor(32); defer-max; interior-tile fast path. Best-measured variant.
__global__ __launch_bounds__(512, 2) void k_attn(u16* __restrict__ QKV,
                                                 const float* __restrict__ cs,
                                                 const float* __restrict__ sn) {
  const int bx = blockIdx.x, h = blockIdx.y, b = blockIdx.z;
  const int qb = (b >= 2) ? 7 - bx : bx;        // cost-balanced remap
  const int tid = threadIdx.x;
  const int lane = tid & 63, w = tid >> 6;      // 8 waves
  const int l31 = lane & 31, hi = lane >> 5;
  const int kh = h >> 2;
  const int qs = qb * 256 + w * 32;
  __shared__ __align__(16) u16 Klds[3][64 * 128];  // [kv][d], swizzled, 3 buffers
  __shared__ __align__(16) u16 Vt[128 * 64];       // [d][kv], swizzled, 1 buffer
  char* Vb = (char*)Vt;
  const float SCL2 = 0.08838834764831845f * 1.4426950408889634f;  // scale*log2(e)
  const size_t bL = (size_t)b * L_S;
  const int q = qs + l31;
  const size_t rowQ = (bL + q) * QW + h * HD;
  // Q load + fused interleaved RoPE (d = ds*16+hi*8+j; pair f = d>>1)
  short8 qf[8];
#pragma unroll
  for (int ds = 0; ds < 8; ++ds) {
    short8 qr = *(const short8*)(QKV + rowQ + ds * 16 + hi * 8);
    const int f0 = ds * 8 + hi * 4;                   // first pair index (mult of 4)
    float4 c4 = *(const float4*)(cs + (size_t)q * 64 + f0);
    float4 s4 = *(const float4*)(sn + (size_t)q * 64 + f0);
    ushort8 qo;
#pragma unroll
    for (int e = 0; e < 4; ++e) {
      float xr = bf16_f32((u16)qr[2 * e]);
      float xi = bf16_f32((u16)qr[2 * e + 1]);
      float co = (e == 0) ? c4.x : (e == 1) ? c4.y : (e == 2) ? c4.z : c4.w;
      float si = (e == 0) ? s4.x : (e == 1) ? s4.y : (e == 2) ? s4.z : s4.w;
      qo[2 * e]     = f32_bf16(xr * co - xi * si);
      qo[2 * e + 1] = f32_bf16(xr * si + xi * co);
    }
    qf[ds] = __builtin_bit_cast(short8, qo);
  }
  f32x16 o[4];
#pragma unroll
  for (int dt = 0; dt < 4; ++dt)
#pragma unroll
    for (int r = 0; r < 16; ++r) o[dt][r] = 0.f;
  float m2 = -3e38f, lsum = 0.f;  // per-lane stats for this lane's q (log2 domain)
  int t0 = qb * 256 - (WIN - 1);
  if (t0 < 0) t0 = 0;
  t0 >>= 6;
  const int t1 = 4 * qb + 3;  // == (qb*256+255)>>6 (always >= t0+3)
  short8 vreg[2];

  auto ISSUE_K = [&](int t, int buf) {
    char* Kb = (char*)Klds + buf * 16384;
#pragma unroll
    for (int rr = 0; rr < 2; ++rr) {
      int row = rr * 32 + (tid >> 4);              // 0..63
      int colb = ((tid & 15) * 16) ^ ((row & 7) << 4);  // inverse-swizzled source
      gload_lds16(QKV + (bL + t * 64 + row) * QW + E_D + kh * HD + (colb >> 1),
                  Kb + rr * 8192 + w * 1024 + (lane << 4));
    }
  };
  auto LOAD_V = [&](int t) {
#pragma unroll
    for (int rr = 0; rr < 2; ++rr)
      vreg[rr] = *(const short8*)(QKV + (bL + t * 64 + lane) * QW + E_D + 512 + kh * HD +
                                  ((w * 2 + rr) * 8));
  };
  auto WRITE_V = [&]() {
#pragma unroll
    for (int rr = 0; rr < 2; ++rr) {
      int db = (w * 2 + rr) * 8;                   // multiple of 8 -> row&7 == e
#pragma unroll
      for (int e = 0; e < 8; ++e)
        *(u16*)(Vb + ((((db + e) * 128) + lane * 2) ^ (e << 4))) = (u16)vreg[rr][e];
    }
  };

  // --- prologue ---
  LOAD_V(t0);
  ISSUE_K(t0, t0 % 3);
  ISSUE_K(t0 + 1, (t0 + 1) % 3);
  __syncthreads();          // full drain (prologue only); Vt write next
  WRITE_V();                // Vt = V(t0); published by barrier1 of iter t0

  for (int t = t0; t <= t1; ++t) {
    const int kv0 = t * 64;
    const bool haveV = (t + 1 <= t1);
    const bool haveK = (t + 2 <= t1);
    if (haveV) LOAD_V(t + 1);                 // issue V FIRST
    if (haveK) ISSUE_K(t + 2, (t + 2) % 3);   // then K (stays in flight longer)
    const bool act = (kv0 <= qs + 31) && (kv0 + 63 > qs - WIN);
    const bool full = (kv0 + 63 <= qs) && (kv0 > qs + 31 - WIN);  // no masking needed
    u32x4 pa[4];  // assembled PV A-frags (bf16 x8 each)
    if (act) {
      const char* Kb = (const char*)Klds + (t % 3) * 16384;
      f32x16 s[2];
#pragma unroll
      for (int g = 0; g < 2; ++g)
#pragma unroll
        for (int r = 0; r < 16; ++r) s[g][r] = 0.f;
#pragma unroll
      for (int g = 0; g < 2; ++g) {
        const int r = g * 32 + l31;                  // K row this lane reads
        const int rsw = (r & 7) << 4;
#pragma unroll
        for (int ds = 0; ds < 8; ++ds) {
          short8 kf = *(const short8*)(Kb + (r * 256 + ((ds * 32 + hi * 16) ^ rsw)));
          s[g] = __builtin_amdgcn_mfma_f32_32x32x16_bf16(kf, qf[ds], s[g], 0, 0, 0);
        }
      }
      float v[2][16];
      float mx = -3e38f;
      if (full) {
#pragma unroll
        for (int g = 0; g < 2; ++g)
#pragma unroll
          for (int r = 0; r < 16; ++r) {
            float vv = s[g][r] * SCL2;
            v[g][r] = vv;
            mx = fmaxf(mx, vv);
          }
      } else {
#pragma unroll
        for (int g = 0; g < 2; ++g)
#pragma unroll
          for (int r = 0; r < 16; ++r) {
            int kg = kv0 + g * 32 + (r & 3) + 8 * (r >> 2) + 4 * hi;
            bool a = (kg <= q) && (kg > q - WIN);
            float vv = a ? s[g][r] * SCL2 : -3e38f;
            v[g][r] = vv;
            mx = fmaxf(mx, vv);
          }
      }
      mx = fmaxf(mx, __shfl_xor(mx, 32));            // partner has other kv half
      if (__ballot(mx > m2 + 11.5415603f)) {
        float mn = fmaxf(m2, mx);
        float alpha = exp2f(m2 - mn);
        m2 = mn;
        lsum *= alpha;
#pragma unroll
        for (int r = 0; r < 16; ++r) {
          float alr = __shfl(alpha, (r & 3) + 8 * (r >> 2) + 4 * hi);
#pragma unroll
          for (int dt = 0; dt < 4; ++dt) o[dt][r] *= alr;
        }
      }
      float rs = 0.f;
      if (full) {
#pragma unroll
        for (int g = 0; g < 2; ++g)
#pragma unroll
          for (int r = 0; r < 16; ++r) {
            float pe = exp2f(v[g][r] - m2);
            v[g][r] = pe;
            rs += pe;
          }
      } else {
#pragma unroll
        for (int g = 0; g < 2; ++g)
#pragma unroll
          for (int r = 0; r < 16; ++r) {
            float pe = (v[g][r] > -1e37f) ? exp2f(v[g][r] - m2) : 0.f;
            v[g][r] = pe;
            rs += pe;
          }
      }
      rs += __shfl_xor(rs, 32);
      lsum += rs;
#pragma unroll
      for (int g = 0; g < 2; ++g) {
        u32 W[8];
#pragma unroll
        for (int qi = 0; qi < 4; ++qi) {
          W[2 * qi]     = pack_bf16_pair(v[g][4 * qi + 0], v[g][4 * qi + 1]);
          W[2 * qi + 1] = pack_bf16_pair(v[g][4 * qi + 2], v[g][4 * qi + 3]);
        }
        u32 R[4];
        R[0] = __shfl_xor(hi ? W[0] : W[2], 32);
        R[1] = __shfl_xor(hi ? W[1] : W[3], 32);
        R[2] = __shfl_xor(hi ? W[4] : W[6], 32);
        R[3] = __shfl_xor(hi ? W[5] : W[7], 32);
#pragma unroll
        for (int ksl = 0; ksl < 2; ++ksl) {
          u32x4 fr;
          if (hi == 0) {
            fr[0] = W[4 * ksl]; fr[1] = W[4 * ksl + 1];
            fr[2] = R[2 * ksl]; fr[3] = R[2 * ksl + 1];
          } else {
            fr[0] = R[2 * ksl]; fr[1] = R[2 * ksl + 1];
            fr[2] = W[4 * ksl + 2]; fr[3] = W[4 * ksl + 3];
          }
          pa[g * 2 + ksl] = fr;
        }
      }
    }
    // barrier1: publishes Vt (writer's ds_writes drained) + orders LDS reuse
    asm volatile("s_waitcnt lgkmcnt(0)" ::: "memory");
    __builtin_amdgcn_sched_barrier(0);
    __builtin_amdgcn_s_barrier();
    __builtin_amdgcn_sched_barrier(0);
    if (act) {
      // --- O += P V from Vt ---
      __builtin_amdgcn_s_setprio(1);
#pragma unroll
      for (int dt = 0; dt < 4; ++dt) {
        const int d = dt * 32 + l31;
        const int dsw = (d & 7) << 4;
#pragma unroll
        for (int ks = 0; ks < 4; ++ks) {
          short8 vf = *(const short8*)(Vb + (d * 128 + ((ks * 32 + hi * 16) ^ dsw)));
          o[dt] = __builtin_amdgcn_mfma_f32_32x32x16_bf16(
              __builtin_bit_cast(short8, pa[ks]), vf, o[dt], 0, 0, 0);
        }
      }
      __builtin_amdgcn_s_setprio(0);
    }
    // barrier2: counted vmcnt — drain K(t+1) (next QK input), keep newest in flight
    if (haveK)
      asm volatile("s_waitcnt vmcnt(4)" ::: "memory");
    else if (haveV)
      asm volatile("s_waitcnt vmcnt(2)" ::: "memory");
    else
      asm volatile("s_waitcnt vmcnt(0)" ::: "memory");
    __builtin_amdgcn_sched_barrier(0);
    __builtin_amdgcn_s_barrier();
    __builtin_amdgcn_sched_barrier(0);
    if (haveV) WRITE_V();   // Vt = V(t+1); readers gated by barrier1(t+1)
  }
  float inv = 1.0f / lsum;
#pragma unroll
  for (int r = 0; r < 16; ++r) {
    int ridx = (r & 3) + 8 * (r >> 2) + 4 * hi;
    float invr = __shfl(inv, ridx);
    size_t rowO = (bL + qs + ridx) * QW + h * HD + l31;
#pragma unroll
    for (int dt = 0; dt < 4; ++dt)
      QKV[rowO + dt * 32] = f32_bf16(o[dt][r] * invr);
  }
}

extern "C" void kernel_launch(void* const* d_in, const int* in_sizes, int n_in,
                              void* d_out, int out_size, void* d_ws, size_t ws_size,
                              hipStream_t stream) {
  const float* x  = (const float*)d_in[0];
  const float* Wq = (const float*)d_in[1];
  const float* Wk = (const float*)d_in[2];
  const float* Wv = (const float*)d_in[3];
  const float* Wo = (const float*)d_in[4];
  char* ws = (char*)d_ws;
  // Workspace layout (total 105,906,176 B). If the harness workspace is too
  // small, bail out cleanly (validation fails loudly instead of GPU faulting).
  if (ws_size < 105906176u) return;
  u16* xb    = (u16*)(ws);                    // 8192*2048*2 = 33554432
  u16* Wqkv  = (u16*)(ws + 33554432);         // 3072*2048*2 = 12582912
  u16* Wob   = (u16*)(ws + 46137344);         // 2048*2048*2 =  8388608
  u16* QKV   = (u16*)(ws + 54525952);         // 8192*3072*2 = 50331648
  float* cs  = (float*)(ws + 104857600);      // 131072*4    =   524288
  float* sn  = (float*)(ws + 105381888);      // total end 105906176 B

  // bf16 casts + RoPE table (weights packed: Wq 0..2047 | Wk 2048..2559 | Wv 2560..3071)
  k_cast<<<8192, 256, 0, stream>>>(x, xb, 16777216 / 8);
  k_cast_w<<<5632, 256, 0, stream>>>(Wq, Wk, Wv, Wo, Wqkv, Wob, cs, sn);
  // fused QKV projection: [Q|K|V] = xb @ Wqkv^T (256x128 tiles: 32 m x 24 n = 768 wg)
  k_gemm8<0, 128><<<768, 512, 0, stream>>>(xb, 2048, Wqkv, 2048, QKV, QW, 2048);
  // RoPE in place on K region only (Q rope fused into k_attn)
  k_rope_k<<<8192, 256, 0, stream>>>(QKV, cs, sn);
  // flash attention (Q-rope fused, counted-vmcnt pipeline); Z overwrites Q region
  k_attn<<<dim3(8, 16, 4), 512, 0, stream>>>(QKV, cs, sn);
  // out = Z @ Wo^T (fp32 out; 256x256 tiles: 32 m x 8 n = 256 wg, exact fit)
  k_gemm8<1, 256><<<256, 512, 0, stream>>>(QKV, QW, Wob, 2048, d_out, 2048, 2048);
}